// Round 1
// baseline (87.978 us; speedup 1.0000x reference)
//
#include <hip/hip_runtime.h>

// BPR loss: out = (2/n^2) * sum_{i,j: t[j] > t[i]} softplus(in[i] - in[j])
//
// Base-2 reformulation: softplus(x) = ln2 * (max(y,0) + log2(1 + 2^(-|y|)))
// with y = x * log2e. Pre-scale inputs by log2e once; apply ln2 at the end.
// v_exp_f32 / v_log_f32 are the hw 2^x / log2 ops; -|d| folds into src mods.

constexpr float LOG2E = 1.44269504088896340736f;
constexpr float LN2   = 0.69314718055994530942f;

__global__ void zero_out_kernel(float* out, int n) {
    int i = blockIdx.x * blockDim.x + threadIdx.x;
    if (i < n) out[i] = 0.0f;
}

template<int TI, int JT>
__global__ __launch_bounds__(256)
void bpr_kernel(const float* __restrict__ inp, const float* __restrict__ tgt,
                float* __restrict__ out, int n) {
    __shared__ float2 sj[JT];           // (u_j, t_j) for this block's j-chunk
    const int tid   = threadIdx.x;
    const int jbase = blockIdx.x * JT;
    const int ibase = blockIdx.y * (256 * TI);

    // stage j-chunk into LDS (coalesced global reads)
    for (int j = tid; j < JT; j += 256) {
        int gj = jbase + j;
        sj[j] = make_float2(inp[gj] * LOG2E, tgt[gj]);
    }

    // per-thread i-fragment in registers (coalesced: tid + k*256)
    float ui[TI], ti[TI];
#pragma unroll
    for (int k = 0; k < TI; ++k) {
        int gi = ibase + k * 256 + tid;
        ui[k] = inp[gi] * LOG2E;
        ti[k] = tgt[gi];
    }
    __syncthreads();

    float acc[TI];
#pragma unroll
    for (int k = 0; k < TI; ++k) acc[k] = 0.0f;

#pragma unroll 4
    for (int j = 0; j < JT; ++j) {
        float2 v = sj[j];               // uniform address -> LDS broadcast
        float uj = v.x, tj = v.y;
#pragma unroll
        for (int k = 0; k < TI; ++k) {
            float d  = ui[k] - uj;
            float e  = __builtin_amdgcn_exp2f(-__builtin_fabsf(d)); // v_exp_f32 w/ -|.| mods
            float sp = fmaxf(d, 0.0f) + __builtin_amdgcn_logf(1.0f + e); // v_log_f32
            acc[k] += (tj > ti[k]) ? sp : 0.0f;
        }
    }

    float s = 0.0f;
#pragma unroll
    for (int k = 0; k < TI; ++k) s += acc[k];

    // wave64 shuffle reduction
#pragma unroll
    for (int off = 32; off > 0; off >>= 1)
        s += __shfl_down(s, off, 64);

    __shared__ float swave[4];
    int wave = tid >> 6;
    if ((tid & 63) == 0) swave[wave] = s;
    __syncthreads();
    if (tid == 0) {
        float bs = swave[0] + swave[1] + swave[2] + swave[3];
        float scale = LN2 * 2.0f / ((float)n * (float)n);
        atomicAdd(out, bs * scale);
    }
}

extern "C" void kernel_launch(void* const* d_in, const int* in_sizes, int n_in,
                              void* d_out, int out_size, void* d_ws, size_t ws_size,
                              hipStream_t stream) {
    const float* inp = (const float*)d_in[0];
    const float* tgt = (const float*)d_in[1];
    float* out = (float*)d_out;
    const int n = in_sizes[0];          // 16384

    zero_out_kernel<<<1, 64, 0, stream>>>(out, out_size);

    constexpr int TI = 4;               // i-values per thread (registers)
    constexpr int JT = 512;             // j-chunk staged in LDS
    dim3 grid(n / JT, n / (256 * TI));  // (32, 16) = 512 blocks
    bpr_kernel<TI, JT><<<grid, 256, 0, stream>>>(inp, tgt, out, n);
}

// Round 2
// 58.410 us; speedup vs baseline: 1.5062x; 1.5062x over previous
//
#include <hip/hip_runtime.h>

// BPR loss: out = (2/n^2) * sum_{(i,j): t[j] > t[i]} softplus(in[i] - in[j])
//
// Antisymmetric halving: for each unordered pair {i,j} exactly one direction
// passes the mask (ties ~1 pair, contribute <1e-7 — ignored). With
// y = x*log2e, softplus(x)/ln2 = log2(1+2^-|y|) + 0.5|y| + 0.5*(sign-selected y).
// One visit per unordered pair: 7 VALU + 2 transcendental (v_exp/v_log).

constexpr float LOG2E = 1.44269504088896340736f;
constexpr float LN2   = 0.69314718055994530942f;

__global__ void zero_out_kernel(float* out, int n) {
    int i = blockIdx.x * blockDim.x + threadIdx.x;
    if (i < n) out[i] = 0.0f;
}

// Tile size 512 on both axes; 256 threads, 2 i-rows/thread; j-chunk 256 in LDS.
// Grid: 2 blocks (j-halves) per triangular tile pair (bi <= bj).
__global__ __launch_bounds__(256)
void bpr_tri_kernel(const float* __restrict__ inp, const float* __restrict__ tgt,
                    float* __restrict__ out, int n, int nt, float scale) {
    // decode linear block id -> (bi, bj) upper triangle incl. diagonal, + j-half
    int p    = blockIdx.x >> 1;
    int half = blockIdx.x & 1;
    int bi = 0, rem = p;
    while (rem >= nt - bi) { rem -= nt - bi; ++bi; }   // <=32 scalar iters
    int bj = bi + rem;

    const int tid   = threadIdx.x;
    const int ibase = bi * 512;
    const int jbase = bj * 512 + half * 256;

    __shared__ float2 sj[256];
    {
        int gj = jbase + tid;
        sj[tid] = make_float2(inp[gj] * LOG2E, tgt[gj]);
    }
    const int gi0 = ibase + tid;
    const int gi1 = ibase + 256 + tid;
    const float u0 = inp[gi0] * LOG2E, t0 = tgt[gi0];
    const float u1 = inp[gi1] * LOG2E, t1 = tgt[gi1];
    __syncthreads();

    float acc0 = 0.0f, acc1 = 0.0f;

    if (bi != bj) {
        // disjoint tiles: every (i-row, j) slot is a distinct unordered pair
#pragma unroll 8
        for (int j = 0; j < 256; ++j) {
            float2 v = sj[j];                 // uniform addr -> LDS broadcast
            float uj = v.x, tj = v.y;
            {
                float d  = u0 - uj;
                float ad = __builtin_fabsf(d);
                float e  = __builtin_amdgcn_exp2f(-ad);
                float L  = __builtin_amdgcn_logf(1.0f + e);   // v_log_f32 = log2
                float sym = fmaf(0.5f, ad, L);
                float sd  = (tj > t0) ? d : -d;
                acc0 += fmaf(0.5f, sd, sym);
            }
            {
                float d  = u1 - uj;
                float ad = __builtin_fabsf(d);
                float e  = __builtin_amdgcn_exp2f(-ad);
                float L  = __builtin_amdgcn_logf(1.0f + e);
                float sym = fmaf(0.5f, ad, L);
                float sd  = (tj > t1) ? d : -d;
                acc1 += fmaf(0.5f, sd, sym);
            }
        }
    } else {
        // diagonal tile: count each unordered pair once via j > i
#pragma unroll 8
        for (int j = 0; j < 256; ++j) {
            float2 v = sj[j];
            float uj = v.x, tj = v.y;
            int gj = jbase + j;
            {
                float d  = u0 - uj;
                float ad = __builtin_fabsf(d);
                float e  = __builtin_amdgcn_exp2f(-ad);
                float L  = __builtin_amdgcn_logf(1.0f + e);
                float sym = fmaf(0.5f, ad, L);
                float sd  = (tj > t0) ? d : -d;
                float c   = fmaf(0.5f, sd, sym);
                acc0 += (gj > gi0) ? c : 0.0f;
            }
            {
                float d  = u1 - uj;
                float ad = __builtin_fabsf(d);
                float e  = __builtin_amdgcn_exp2f(-ad);
                float L  = __builtin_amdgcn_logf(1.0f + e);
                float sym = fmaf(0.5f, ad, L);
                float sd  = (tj > t1) ? d : -d;
                float c   = fmaf(0.5f, sd, sym);
                acc1 += (gj > gi1) ? c : 0.0f;
            }
        }
    }

    float s = acc0 + acc1;
#pragma unroll
    for (int off = 32; off > 0; off >>= 1)
        s += __shfl_down(s, off, 64);

    __shared__ float swave[4];
    if ((tid & 63) == 0) swave[tid >> 6] = s;
    __syncthreads();
    if (tid == 0) {
        float bs = swave[0] + swave[1] + swave[2] + swave[3];
        atomicAdd(out, bs * scale);
    }
}

extern "C" void kernel_launch(void* const* d_in, const int* in_sizes, int n_in,
                              void* d_out, int out_size, void* d_ws, size_t ws_size,
                              hipStream_t stream) {
    const float* inp = (const float*)d_in[0];
    const float* tgt = (const float*)d_in[1];
    float* out = (float*)d_out;
    const int n = in_sizes[0];          // 16384

    zero_out_kernel<<<1, 64, 0, stream>>>(out, out_size);

    const int nt = n / 512;             // 32 tiles
    const int nblocks = nt * (nt + 1) / 2 * 2;   // 528 pairs x 2 j-halves = 1056
    const float scale = LN2 * 2.0f / ((float)n * (float)n);
    bpr_tri_kernel<<<nblocks, 256, 0, stream>>>(inp, tgt, out, n, nt, scale);
}

// Round 3
// 53.675 us; speedup vs baseline: 1.6391x; 1.0882x over previous
//
#include <hip/hip_runtime.h>

// BPR loss: out = (2/n^2) * sum_{(i,j): t[j] > t[i]} softplus(in[i] - in[j])
//
// Antisymmetric halving: visit each unordered pair once.
// y = x*log2e; softplus(x)/ln2 = log2(1+2^-|y|) + 0.5|y| + 0.5*(sign-sel y).
// Per pair: 7 regular VALU + 2 transcendental (v_exp_f32 / v_log_f32).
//
// Occupancy: 256x256 tiles -> nt=64, 2080 triangular blocks x 4 waves
// = 8.1 waves/SIMD (fills the 32-wave/CU budget; VGPR=32 permits it).

constexpr float LOG2E = 1.44269504088896340736f;
constexpr float LN2   = 0.69314718055994530942f;

__global__ __launch_bounds__(256)
void bpr_tri_kernel(const float* __restrict__ inp, const float* __restrict__ tgt,
                    float* __restrict__ out, int nt, float scale) {
    // linear block id -> (bi, bj), upper triangle incl. diagonal
    int bi = 0, rem = blockIdx.x;
    while (rem >= nt - bi) { rem -= nt - bi; ++bi; }
    const int bj = bi + rem;

    const int tid   = threadIdx.x;
    const int ibase = bi * 256;
    const int jbase = bj * 256;

    __shared__ float2 sj[256];
    {
        int gj = jbase + tid;
        sj[tid] = make_float2(inp[gj] * LOG2E, tgt[gj]);
    }
    const int   gi = ibase + tid;
    const float u0 = inp[gi] * LOG2E;
    const float t0 = tgt[gi];
    __syncthreads();

    float acc = 0.0f;

    if (bi != bj) {
#pragma unroll 8
        for (int j = 0; j < 256; ++j) {
            float2 v = sj[j];                 // uniform addr -> LDS broadcast
            float d  = u0 - v.x;
            float ad = __builtin_fabsf(d);
            float e  = __builtin_amdgcn_exp2f(-ad);
            float L  = __builtin_amdgcn_logf(1.0f + e);   // v_log_f32 = log2
            float sym = fmaf(0.5f, ad, L);
            float sd  = (v.y > t0) ? d : -d;
            acc += fmaf(0.5f, sd, sym);
        }
    } else {
        // diagonal tile: count each unordered pair once via j > i
#pragma unroll 8
        for (int j = 0; j < 256; ++j) {
            float2 v = sj[j];
            float d  = u0 - v.x;
            float ad = __builtin_fabsf(d);
            float e  = __builtin_amdgcn_exp2f(-ad);
            float L  = __builtin_amdgcn_logf(1.0f + e);
            float sym = fmaf(0.5f, ad, L);
            float sd  = (v.y > t0) ? d : -d;
            float c   = fmaf(0.5f, sd, sym);
            acc += (j > tid) ? c : 0.0f;
        }
    }

    // wave64 shuffle reduction
#pragma unroll
    for (int off = 32; off > 0; off >>= 1)
        acc += __shfl_down(acc, off, 64);

    __shared__ float swave[4];
    if ((tid & 63) == 0) swave[tid >> 6] = acc;
    __syncthreads();
    if (tid == 0) {
        float bs = swave[0] + swave[1] + swave[2] + swave[3];
        atomicAdd(out, bs * scale);
    }
}

extern "C" void kernel_launch(void* const* d_in, const int* in_sizes, int n_in,
                              void* d_out, int out_size, void* d_ws, size_t ws_size,
                              hipStream_t stream) {
    const float* inp = (const float*)d_in[0];
    const float* tgt = (const float*)d_in[1];
    float* out = (float*)d_out;
    const int n = in_sizes[0];          // 16384

    hipMemsetAsync(out, 0, out_size * sizeof(float), stream);

    const int nt = n / 256;                      // 64 tiles
    const int nblocks = nt * (nt + 1) / 2;       // 2080 blocks
    const float scale = LN2 * 2.0f / ((float)n * (float)n);
    bpr_tri_kernel<<<nblocks, 256, 0, stream>>>(inp, tgt, out, nt, scale);
}

// Round 4
// 47.676 us; speedup vs baseline: 1.8453x; 1.1258x over previous
//
#include <hip/hip_runtime.h>

// BPR loss: out = (2/n^2) * sum_{(i,j): t[j] > t[i]} softplus(in[i] - in[j])
//
// Antisymmetric halving: visit each unordered pair once; exactly one direction
// passes the mask (fp32 ties ~1 pair, contribute <1e-7 -- ignored).
// With y = x*log2e, d = y_i - y_j, e = 2^(-|d|) = exp(-|x_i-x_j|):
//   softplus(x_i - x_j) summed over the passing direction
//     = ln(1+e) + 0.5*ln2*(|d| + sign(t_j - t_i)*d)
// ln(1+e) via cubic poly (max err ~8e-4, output budget 1.8e-2):
//   ln(1+e) ~= e*(C1 + e*(C2 + e*C3))
// Body: 8 regular VALU + 1 v_exp_f32. Three accumulators, no per-pair
// recombination; |d| and -d fold into VOP3 input modifiers.

constexpr float LOG2E = 1.44269504088896340736f;
constexpr float LN2   = 0.69314718055994530942f;
constexpr float C1 = 0.983568f;   // cubic interp of ln(1+e) at {0,1/3,2/3,1}
constexpr float C2 = -0.397138f;
constexpr float C3 = 0.106717f;

__global__ __launch_bounds__(256)
void bpr_tri_kernel(const float* __restrict__ inp, const float* __restrict__ tgt,
                    float* __restrict__ out, int nt, float scale) {
    // linear block id -> (bi, bj), upper triangle incl. diagonal
    int bi = 0, rem = blockIdx.x;
    while (rem >= nt - bi) { rem -= nt - bi; ++bi; }
    const int bj = bi + rem;

    const int tid   = threadIdx.x;
    const int ibase = bi * 256;
    const int jbase = bj * 256;

    __shared__ alignas(16) float2 sj[256];
    sj[tid] = make_float2(inp[jbase + tid] * LOG2E, tgt[jbase + tid]);
    const float u0 = inp[ibase + tid] * LOG2E;
    const float t0 = tgt[ibase + tid];
    __syncthreads();

    float accL = 0.0f;   // sum ln(1+e)
    float accA = 0.0f;   // sum |d|
    float accS = 0.0f;   // sum sign(tj-t0)*d
    const float4* sj4 = (const float4*)sj;   // 2 (u,t) pairs per read

    if (bi != bj) {
#pragma unroll 8
        for (int c = 0; c < 128; ++c) {
            float4 v = sj4[c];
            {
                float d = u0 - v.x;
                float e = __builtin_amdgcn_exp2f(-__builtin_fabsf(d));
                float p = fmaf(C3, e, C2);
                p = fmaf(p, e, C1);
                accL = fmaf(e, p, accL);
                accA += __builtin_fabsf(d);
                accS += (v.y > t0) ? d : -d;
            }
            {
                float d = u0 - v.z;
                float e = __builtin_amdgcn_exp2f(-__builtin_fabsf(d));
                float p = fmaf(C3, e, C2);
                p = fmaf(p, e, C1);
                accL = fmaf(e, p, accL);
                accA += __builtin_fabsf(d);
                accS += (v.w > t0) ? d : -d;
            }
        }
    } else {
        // diagonal tile: count each unordered pair once via j > tid.
        // Masked pairs: zero d and e -> all three contributions vanish
        // (poly has no constant term).
#pragma unroll 8
        for (int c = 0; c < 128; ++c) {
            float4 v = sj4[c];
            {
                bool on = (2 * c) > tid;
                float d = on ? (u0 - v.x) : 0.0f;
                float e = on ? __builtin_amdgcn_exp2f(-__builtin_fabsf(d)) : 0.0f;
                float p = fmaf(C3, e, C2);
                p = fmaf(p, e, C1);
                accL = fmaf(e, p, accL);
                accA += __builtin_fabsf(d);
                accS += (v.y > t0) ? d : -d;
            }
            {
                bool on = (2 * c + 1) > tid;
                float d = on ? (u0 - v.z) : 0.0f;
                float e = on ? __builtin_amdgcn_exp2f(-__builtin_fabsf(d)) : 0.0f;
                float p = fmaf(C3, e, C2);
                p = fmaf(p, e, C1);
                accL = fmaf(e, p, accL);
                accA += __builtin_fabsf(d);
                accS += (v.w > t0) ? d : -d;
            }
        }
    }

    // combine: ln-units total for this thread
    float s = fmaf(0.5f * LN2, accA + accS, accL);

    // wave64 shuffle reduction
#pragma unroll
    for (int off = 32; off > 0; off >>= 1)
        s += __shfl_down(s, off, 64);

    __shared__ float swave[4];
    if ((tid & 63) == 0) swave[tid >> 6] = s;
    __syncthreads();
    if (tid == 0) {
        float bs = swave[0] + swave[1] + swave[2] + swave[3];
        atomicAdd(out, bs * scale);
    }
}

extern "C" void kernel_launch(void* const* d_in, const int* in_sizes, int n_in,
                              void* d_out, int out_size, void* d_ws, size_t ws_size,
                              hipStream_t stream) {
    const float* inp = (const float*)d_in[0];
    const float* tgt = (const float*)d_in[1];
    float* out = (float*)d_out;
    const int n = in_sizes[0];          // 16384

    hipMemsetAsync(out, 0, out_size * sizeof(float), stream);

    const int nt = n / 256;                      // 64 tiles
    const int nblocks = nt * (nt + 1) / 2;       // 2080 blocks
    const float scale = 2.0f / ((float)n * (float)n);
    bpr_tri_kernel<<<nblocks, 256, 0, stream>>>(inp, tgt, out, nt, scale);
}